// Round 4
// baseline (656.865 us; speedup 1.0000x reference)
//
#include <hip/hip_runtime.h>

// Problem constants (fixed by reference): B=16, H=W=256, dx=2/128, dt=1e-3, nt=64
#define NBATCH 16
#define NPIX   65536             // 256*256
#define NTOT   (NBATCH * NPIX)   // 1,048,576

constexpr float DTf    = 0.001f;                         // dt
constexpr float HDTf   = 0.0005f;                        // (float)(0.5*dt)
constexpr float HDT2f  = 5.0000000000000004e-07f;        // (float)(0.5*dt*dt)
constexpr float INV_DX  = 64.0f;                         // 1/dx (exact pow2)
constexpr float INV_DX2 = 4096.0f;                       // 1/dx^2 (exact pow2)
constexpr float TWO_PI  = 6.28318530717958647692f;

constexpr int FWD = -1;
constexpr int INV =  1;

// ---------------------------------------------------------------------------
// 256-point Stockham autosort FFT in LDS (DIF, twiddle-after-subtract).
// One wave (64 lanes) per transform; 2 butterflies/lane/stage; 8 radix-2
// stages ping-ponging a<->b; natural order in AND out (hand-verified on the
// N=4 analog: stage s, butterfly b: j*m = b & ~(m-1); y[b+jm] = c0+c1,
// y[b+jm+m] = tw[jm]*(c0-c1), tw[t] = exp(SIGN*2*pi*i*t/256)).
// Works inside multi-wave blocks: all waves run identical stage counts so
// the __syncthreads() align.
// ---------------------------------------------------------------------------
__device__ __forceinline__ void fft256_stockham(float* ar, float* ai,
                                                float* br, float* bi,
                                                const float* twr, const float* twi,
                                                int lane)
{
  float *xr = ar, *xi = ai, *yr = br, *yi = bi;
#pragma unroll
  for (int s = 0; s < 8; ++s) {
    const int m = 1 << s;
    __syncthreads();
#pragma unroll
    for (int q = 0; q < 2; ++q) {
      const int b  = lane + (q << 6);       // butterfly id in [0,128)
      const int jm = b & ~(m - 1);          // j*m = twiddle index
      const float wr = twr[jm], wi = twi[jm];
      const float c0r = xr[b],       c0i = xi[b];
      const float c1r = xr[b + 128], c1i = xi[b + 128];
      const int i0 = b + jm, i1 = i0 + m;
      yr[i0] = c0r + c1r;
      yi[i0] = c0i + c1i;
      const float dr = c0r - c1r, di = c0i - c1i;
      yr[i1] = wr * dr - wi * di;
      yi[i1] = wr * di + wi * dr;
    }
    float* t;
    t = xr; xr = yr; yr = t;
    t = xi; xi = yi; yi = t;
  }
  __syncthreads();   // 8 swaps -> result back in ar/ai
}

// ---------------------------------------------------------------------------
// Forward row FFT fused with packing z = wx + i*wy AND the sum(wx) reduction
// (one atomicAdd per block; order nondeterminism only perturbs sumv at ulp
// level, far below validation tolerance).
// grid: 4096 blocks (b*256 + y) x 64 threads. All global traffic coalesced.
// ---------------------------------------------------------------------------
__global__ __launch_bounds__(64) void k_fwd_rows_pack(const float* __restrict__ in,
                                                      float2* __restrict__ A,
                                                      float* __restrict__ sum)
{
  __shared__ float ar[256], ai[256], br[256], bi[256], twr[128], twi[128];
  const int tid = threadIdx.x;
  const int row = blockIdx.x;            // b*256 + y
  const int b = row >> 8, y = row & 255;
  const float* wx = in + ((size_t)(b << 2) << 16) + (y << 8);
  const float* wy = in + ((size_t)((b << 2) | 1) << 16) + (y << 8);
  float acc = 0.0f;
  for (int i = tid; i < 256; i += 64) {
    const float v = wx[i];
    ar[i] = v; acc += v;
    ai[i] = wy[i];
  }
  for (int t = tid; t < 128; t += 64) {
    float s, c;
    sincosf((float)FWD * (TWO_PI / 256.0f) * (float)t, &s, &c);
    twr[t] = c; twi[t] = s;
  }
#pragma unroll
  for (int o = 32; o > 0; o >>= 1) acc += __shfl_down(acc, o);
  if (tid == 0) atomicAdd(sum, acc);
  fft256_stockham(ar, ai, br, bi, twr, twi, tid);
  float2* o = A + ((size_t)row << 8);
  for (int i = tid; i < 256; i += 64) o[i] = make_float2(ar[i], ai[i]);
}

// ---------------------------------------------------------------------------
// In-place column FFT, 8-column panel per block. 512 threads = 8 waves; wave
// w transforms panel column w. Global reads/writes are 64B-dense (8 float2
// per row-segment). LDS per-column stride 260 -> store bank = (4c+row)&31,
// <=2 lanes/bank (free, m136). grid: 16 batches * 32 panels = 512 blocks.
// ---------------------------------------------------------------------------
template <int SIGN>
__global__ __launch_bounds__(512) void k_fft_cols_panel(float2* __restrict__ X)
{
  constexpr int CS = 260;
  __shared__ float ar[8 * CS], ai[8 * CS], br[8 * CS], bi[8 * CS];
  __shared__ float twr[128], twi[128];
  const int tid = threadIdx.x;
  const int lane = tid & 63;
  const int wv = tid >> 6;                       // panel column
  const int b = blockIdx.x >> 5;
  const int x0 = (blockIdx.x & 31) << 3;
  float2* base = X + ((size_t)b << 16) + x0;

  for (int i = tid; i < 2048; i += 512) {
    const int row = i >> 3, c = i & 7;
    const float2 v = base[(row << 8) + c];
    ar[c * CS + row] = v.x;
    ai[c * CS + row] = v.y;
  }
  for (int t = tid; t < 128; t += 512) {
    float s, c;
    sincosf((float)SIGN * (TWO_PI / 256.0f) * (float)t, &s, &c);
    twr[t] = c; twi[t] = s;
  }
  fft256_stockham(ar + wv * CS, ai + wv * CS, br + wv * CS, bi + wv * CS,
                  twr, twi, lane);
  for (int i = tid; i < 2048; i += 512) {
    const int row = i >> 3, c = i & 7;
    base[(row << 8) + c] = make_float2(ar[c * CS + row], ai[c * CS + row]);
  }
}

// ---------------------------------------------------------------------------
// Spectral combine: split packed spectrum (Hermitian trick), apply
// hatv = -i*(X*kx + Y*ky)/rad ; DC <- sumv.   A -> Bf
//   X_hat = (Z(k)+conj(Z(-k)))/2 ; Y_hat = (Z(k)-conj(Z(-k)))/(2i)
// ---------------------------------------------------------------------------
__global__ __launch_bounds__(256) void k_combine(const float2* __restrict__ A,
                                                 const float* __restrict__ sum,
                                                 float2* __restrict__ Bf)
{
  const int gid = blockIdx.x * 256 + threadIdx.x;
  const int b = gid >> 16, r = gid & 65535;
  const int ky = r >> 8, kx = r & 255;
  const float2 Zk = A[gid];
  const int ky2 = (256 - ky) & 255, kx2 = (256 - kx) & 255;
  const float2 Zm = A[((size_t)b << 16) + (ky2 << 8) + kx2];
  const float Xr = 0.5f * (Zk.x + Zm.x), Xi = 0.5f * (Zk.y - Zm.y);
  const float Yr = 0.5f * (Zk.y + Zm.y), Yi = 0.5f * (Zm.x - Zk.x);
  // kx,ky = 2*pi*fftfreq(256, d=dx); n*d = 4 exactly -> freq = idx/4 (exact)
  const float fx = 0.25f * (float)(kx < 128 ? kx : kx - 256);
  const float fy = 0.25f * (float)(ky < 128 ? ky : ky - 256);
  const float kxv = TWO_PI * fx, kyv = TWO_PI * fy;
  float2 o;
  if (r == 0) {
    o = make_float2(sum[0], 0.0f);
  } else {
    const float rad = kxv * kxv + kyv * kyv;
    const float sr = Xr * kxv + Yr * kyv;
    const float si = Xi * kxv + Yi * kyv;
    o = make_float2(si / rad, -sr / rad);   // -i*(sr+i*si)/rad
  }
  Bf[gid] = o;
}

// ---------------------------------------------------------------------------
// Inverse ROW FFT fused with extraction: u = Re(.)/65536, ut = wtc*c.
// (ifft2 done as cols-then-rows; separable, order-free.) All coalesced.
// ---------------------------------------------------------------------------
__global__ __launch_bounds__(64) void k_inv_rows_extract(const float2* __restrict__ Bf,
                                                         const float* __restrict__ in,
                                                         float* __restrict__ u,
                                                         float* __restrict__ ut)
{
  __shared__ float ar[256], ai[256], br[256], bi[256], twr[128], twi[128];
  const int tid = threadIdx.x;
  const int row = blockIdx.x;            // b*256 + y
  const int b = row >> 8, y = row & 255;
  const float2* p = Bf + ((size_t)row << 8);
  for (int i = tid; i < 256; i += 64) { const float2 v = p[i]; ar[i] = v.x; ai[i] = v.y; }
  for (int t = tid; t < 128; t += 64) {
    float s, c;
    sincosf((float)INV * (TWO_PI / 256.0f) * (float)t, &s, &c);
    twr[t] = c; twi[t] = s;
  }
  fft256_stockham(ar, ai, br, bi, twr, twi, tid);
  const float* wtc = in + ((size_t)((b << 2) | 2) << 16) + (y << 8);
  const float* vc  = in + ((size_t)((b << 2) | 3) << 16) + (y << 8);
  float* uo  = u  + ((size_t)row << 8);
  float* uto = ut + ((size_t)row << 8);
  for (int i = tid; i < 256; i += 64) {
    uo[i]  = ar[i] * (1.0f / 65536.0f);
    uto[i] = wtc[i] * vc[i];
  }
}

// ---------------------------------------------------------------------------
// EIGHT fused velocity-Verlet steps per launch.
// Dependence cone grows 1 cell/step: u_0 @ halo 9, ut_0/c @ halo 8 for a
// 32x32 tile after 8 steps. Invariant before step j: u_{j-1} valid on
// u-frame [j-1, 50-(j-1))^2; UT (=ut_{j-1}) and LA (=lap(u_{j-1})) valid on
// ut-frame [j-1, 48-(j-1))^2. lap(u_j) overwrites LA IN PLACE in the ut-loop
// (each cell reads only its own LA[s]; the stencil reads Unxt -> race-free),
// eliminating the second lap buffer: LDS = (2*50*51 + 3*48*49)*4 = 48624 B
// -> 3 blocks/CU (12 waves/CU). fp op order matches the reference exactly;
// /dx^2 is an exact pow2 -> multiply. grid: 16*64 = 1024 blocks x 256 thr.
// ---------------------------------------------------------------------------
__global__ __launch_bounds__(256, 3) void k_verlet8(const float* __restrict__ u_in,
                                                    const float* __restrict__ ut_in,
                                                    const float* __restrict__ in,
                                                    float* __restrict__ u_out,
                                                    float* __restrict__ ut_out)
{
  constexpr int HU = 9, SU = 50, SUP = 51;   // u frame: halo 9, padded stride 51
  constexpr int HT = 8, ST = 48, STP = 49;   // ut/c2/lap frame: halo 8, stride 49
  __shared__ float bufU0[SU * SUP], bufU1[SU * SUP];
  __shared__ float UT[ST * STP], C2[ST * STP], LA[ST * STP];
  const int tid = threadIdx.x;
  const int blk = blockIdx.x;
  const int b = blk >> 6, t = blk & 63;
  const int ty0 = (t >> 3) << 5, tx0 = (t & 7) << 5;
  const float* ub  = u_in  + ((size_t)b << 16);
  const float* utb = ut_in + ((size_t)b << 16);
  const float* vb  = in + ((size_t)((b << 2) | 3) << 16);   // vel channel

  for (int i = tid; i < SU * SU; i += 256) {
    const int iy = i / SU, ix = i - iy * SU;
    const int gy = (ty0 + iy - HU) & 255, gx = (tx0 + ix - HU) & 255;
    bufU0[iy * SUP + ix] = ub[(gy << 8) + gx];
  }
  for (int i = tid; i < ST * ST; i += 256) {
    const int iy = i / ST, ix = i - iy * ST;
    const int gy = (ty0 + iy - HT) & 255, gx = (tx0 + ix - HT) & 255;
    const int g = (gy << 8) + gx;
    UT[iy * STP + ix] = utb[g];
    const float c = vb[g];
    C2[iy * STP + ix] = c * c;
  }
  __syncthreads();

  // Reference fp order: (((((L - 2v) + R) + Up) - 2v) + Dn) * (1/dx^2)
  auto LAP = [](const float* U, int iy, int ix) -> float {
    const float v  = U[iy * SUP + ix];
    const float t2 = 2.0f * v;
    return (((((U[iy * SUP + ix - 1] - t2) + U[iy * SUP + ix + 1])
              + U[(iy - 1) * SUP + ix]) - t2) + U[(iy + 1) * SUP + ix]) * INV_DX2;
  };

  float* Ucur = bufU0; float* Unxt = bufU1;

  // lap(u_0) on full ut-frame (halo 8)
  for (int i = tid; i < ST * ST; i += 256) {
    const int iy = i / ST, ix = i - iy * ST;
    LA[iy * STP + ix] = LAP(Ucur, iy + 1, ix + 1);
  }
  __syncthreads();

  for (int j = 1; j <= 8; ++j) {
    // u_j = u + dt*ut + (hdt2*c2)*lap0   on u-frame [j, SU-j)^2
    for (int i = tid; i < SU * SU; i += 256) {
      const int iy = i / SU, ix = i - iy * SU;
      if (iy >= j && iy < SU - j && ix >= j && ix < SU - j) {
        const int s = (iy - 1) * STP + (ix - 1);   // ut-frame index
        Unxt[iy * SUP + ix] = Ucur[iy * SUP + ix] + DTf * UT[s] + HDT2f * C2[s] * LA[s];
      }
    }
    __syncthreads();
    // lap1 = lap(u_j); ut_j = ut + (hdt*c2)*(lap0+lap1); LA <- lap1 in place
    for (int i = tid; i < ST * ST; i += 256) {
      const int iy = i / ST, ix = i - iy * ST;
      if (iy >= j && iy < ST - j && ix >= j && ix < ST - j) {
        const int s = iy * STP + ix;
        const float lb = LAP(Unxt, iy + 1, ix + 1);
        UT[s] = UT[s] + HDTf * C2[s] * (LA[s] + lb);
        LA[s] = lb;
      }
    }
    __syncthreads();
    float* tp = Ucur; Ucur = Unxt; Unxt = tp;   // u_j -> current
  }

  // u_8 valid @ u-frame [8,42) (tile+halo1), ut_8 @ ut-frame [8,40) (tile)
  for (int i = tid; i < 1024; i += 256) {
    const int oy = i >> 5, ox = i & 31;
    const int g = ((ty0 + oy) << 8) + (tx0 + ox);
    u_out [((size_t)b << 16) + g] = Ucur[(oy + HU) * SUP + (ox + HU)];
    ut_out[((size_t)b << 16) + g] = UT[(oy + HT) * STP + (ox + HT)];
  }
}

// ---------------------------------------------------------------------------
// Final energy components + output assembly. Reads the D2D-copied final
// state in ws, writes d_out only -> no inter-block read/write hazard.
// ---------------------------------------------------------------------------
__global__ __launch_bounds__(256) void k_energy(const float* __restrict__ u,
                                                const float* __restrict__ ut,
                                                const float* __restrict__ in,
                                                float* __restrict__ out)
{
  const int gid = blockIdx.x * 256 + threadIdx.x;
  const int b = gid >> 16, r = gid & 65535;
  const int y = r >> 8, x = r & 255;
  const size_t base = (size_t)b << 16;
  const float uc = u[base + r];
  const float wxv = (x == 0) ? 0.0f : (uc - u[base + r - 1])   * INV_DX;
  const float wyv = (y == 0) ? 0.0f : (uc - u[base + r - 256]) * INV_DX;
  const float utv = ut[base + r];
  const float c = in[((size_t)((b << 2) | 3) << 16) + r];
  out[((size_t)(b << 2) << 16) + r]       = wxv;
  out[((size_t)((b << 2) | 1) << 16) + r] = wyv;
  out[((size_t)((b << 2) | 2) << 16) + r] = utv / c;
  out[((size_t)((b << 2) | 3) << 16) + r] = c;
}

// ---------------------------------------------------------------------------
// Buffer plan — ws requirement is only 8 MB; d_out (16 MB, fully rewritten
// at the end) doubles as scratch. Lifetimes:
//   d_out[0:8MB)  : A (fwd spectrum)            ... dead after k_combine
//                   then u0/ut0 (even Verlet)   ... dead after D2D copy
//   d_out[2*NTOT] : sumv scalar (memset -> k_combine; clobbered only by
//                   k_energy's final writes)
//   ws[0:8MB)     : Bf (inv spectrum)           ... dead after extract
//                   then u1/ut1 (odd Verlet)    ... dead after last step
//                   then final-state copy for k_energy
// Pipeline: memset -> rowFFT+pack+sum -> colFFT -> combine -> colFFT' ->
//   rowFFT'+extract(->d_out lo) -> 8x verlet8 (ends d_out lo) ->
//   D2D copy (d_out lo -> ws) -> energy(ws -> d_out).
// ---------------------------------------------------------------------------
extern "C" void kernel_launch(void* const* d_in, const int* in_sizes, int n_in,
                              void* d_out, int out_size, void* d_ws, size_t ws_size,
                              hipStream_t stream)
{
  const float* in = (const float*)d_in[0];
  float* out = (float*)d_out;
  char* ws = (char*)d_ws;

  float2* A   = (float2*)d_out;                 // d_out[0:8MB)
  float*  u0  = (float*)d_out;                  // same 8MB, after A dies
  float*  ut0 = u0 + NTOT;
  float*  sum = (float*)d_out + 2 * NTOT;       // 4 B at d_out[8MB)

  float2* Bf  = (float2*)ws;                    // ws[0:8MB)
  float*  u1  = (float*)ws;                     // same 8MB, after Bf dies
  float*  ut1 = u1 + NTOT;

  hipMemsetAsync(sum, 0, sizeof(float), stream);

  k_fwd_rows_pack<<<NBATCH * 256, 64, 0, stream>>>(in, A, sum);
  k_fft_cols_panel<FWD><<<NBATCH * 32, 512, 0, stream>>>(A);
  k_combine<<<NTOT / 256, 256, 0, stream>>>(A, sum, Bf);
  k_fft_cols_panel<INV><<<NBATCH * 32, 512, 0, stream>>>(Bf);
  k_inv_rows_extract<<<NBATCH * 256, 64, 0, stream>>>(Bf, in, u0, ut0);

  // 64 Verlet steps = 8 launches x 8 fused steps, ping-pong; ends in (u0,ut0)
  for (int s = 0; s < 8; ++s) {
    if (s & 1) k_verlet8<<<NBATCH * 64, 256, 0, stream>>>(u1, ut1, in, u0, ut0);
    else       k_verlet8<<<NBATCH * 64, 256, 0, stream>>>(u0, ut0, in, u1, ut1);
  }

  // Move final state out of d_out so k_energy has no read/write overlap.
  hipMemcpyAsync(ws, d_out, (size_t)2 * NTOT * sizeof(float),
                 hipMemcpyDeviceToDevice, stream);

  k_energy<<<NTOT / 256, 256, 0, stream>>>(u1, ut1, in, out);
}

// Round 8
// 307.248 us; speedup vs baseline: 2.1379x; 2.1379x over previous
//
#include <hip/hip_runtime.h>

// Problem constants (fixed by reference): B=16, H=W=256, dx=2/128, dt=1e-3, nt=64
#define NBATCH 16
#define NPIX   65536             // 256*256
#define NTOT   (NBATCH * NPIX)   // 1,048,576

constexpr float DTf    = 0.001f;                         // dt
constexpr float HDTf   = 0.0005f;                        // (float)(0.5*dt)
constexpr float HDT2f  = 5.0000000000000004e-07f;        // (float)(0.5*dt*dt)
constexpr float INV_DX  = 64.0f;                         // 1/dx (exact pow2)
constexpr float INV_DX2 = 4096.0f;                       // 1/dx^2 (exact pow2)
constexpr float TWO_PI  = 6.28318530717958647692f;

constexpr int FWD = -1;
constexpr int INV =  1;

// ---------------------------------------------------------------------------
// 256-point Stockham autosort FFT in LDS (DIF, twiddle-after-subtract).
// One wave per transform; natural order in/out; result ends in ar/ai.
// Safe in multi-wave blocks (all waves run identical stage counts).
// ---------------------------------------------------------------------------
__device__ __forceinline__ void fft256_stockham(float* ar, float* ai,
                                                float* br, float* bi,
                                                const float* twr, const float* twi,
                                                int lane)
{
  float *xr = ar, *xi = ai, *yr = br, *yi = bi;
#pragma unroll
  for (int s = 0; s < 8; ++s) {
    const int m = 1 << s;
    __syncthreads();
#pragma unroll
    for (int q = 0; q < 2; ++q) {
      const int b  = lane + (q << 6);       // butterfly id in [0,128)
      const int jm = b & ~(m - 1);          // j*m = twiddle index
      const float wr = twr[jm], wi = twi[jm];
      const float c0r = xr[b],       c0i = xi[b];
      const float c1r = xr[b + 128], c1i = xi[b + 128];
      const int i0 = b + jm, i1 = i0 + m;
      yr[i0] = c0r + c1r;
      yi[i0] = c0i + c1i;
      const float dr = c0r - c1r, di = c0i - c1i;
      yr[i1] = wr * dr - wi * di;
      yi[i1] = wr * di + wi * dr;
    }
    float* t;
    t = xr; xr = yr; yr = t;
    t = xi; xi = yi; yi = t;
  }
  __syncthreads();   // 8 swaps -> result back in ar/ai
}

// ---------------------------------------------------------------------------
// Forward row FFT fused with packing z = wx + i*wy and the sum(wx) reduction.
// grid: 4096 blocks (b*256 + y) x 64 threads.
// ---------------------------------------------------------------------------
__global__ __launch_bounds__(64) void k_fwd_rows_pack(const float* __restrict__ in,
                                                      float2* __restrict__ A,
                                                      float* __restrict__ sum)
{
  __shared__ float ar[256], ai[256], br[256], bi[256], twr[128], twi[128];
  const int tid = threadIdx.x;
  const int row = blockIdx.x;            // b*256 + y
  const int b = row >> 8, y = row & 255;
  const float* wx = in + ((size_t)(b << 2) << 16) + (y << 8);
  const float* wy = in + ((size_t)((b << 2) | 1) << 16) + (y << 8);
  float acc = 0.0f;
  for (int i = tid; i < 256; i += 64) {
    const float v = wx[i];
    ar[i] = v; acc += v;
    ai[i] = wy[i];
  }
  for (int t = tid; t < 128; t += 64) {
    float s, c;
    sincosf((float)FWD * (TWO_PI / 256.0f) * (float)t, &s, &c);
    twr[t] = c; twi[t] = s;
  }
#pragma unroll
  for (int o = 32; o > 0; o >>= 1) acc += __shfl_down(acc, o);
  if (tid == 0) atomicAdd(sum, acc);
  fft256_stockham(ar, ai, br, bi, twr, twi, tid);
  float2* o = A + ((size_t)row << 8);
  for (int i = tid; i < 256; i += 64) o[i] = make_float2(ar[i], ai[i]);
}

// ---------------------------------------------------------------------------
// In-place forward column FFT, 8-column panel per block. 512 thr = 8 waves.
// LDS per-column stride 260 -> <=2 lanes/bank (free).
// ---------------------------------------------------------------------------
__global__ __launch_bounds__(512) void k_fft_cols_panel_fwd(float2* __restrict__ X)
{
  constexpr int CS = 260;
  __shared__ float ar[8 * CS], ai[8 * CS], br[8 * CS], bi[8 * CS];
  __shared__ float twr[128], twi[128];
  const int tid = threadIdx.x;
  const int lane = tid & 63;
  const int wv = tid >> 6;
  const int b = blockIdx.x >> 5;
  const int x0 = (blockIdx.x & 31) << 3;
  float2* base = X + ((size_t)b << 16) + x0;

  for (int i = tid; i < 2048; i += 512) {
    const int row = i >> 3, c = i & 7;
    const float2 v = base[(row << 8) + c];
    ar[c * CS + row] = v.x;
    ai[c * CS + row] = v.y;
  }
  for (int t = tid; t < 128; t += 512) {
    float s, c;
    sincosf((float)FWD * (TWO_PI / 256.0f) * (float)t, &s, &c);
    twr[t] = c; twi[t] = s;
  }
  fft256_stockham(ar + wv * CS, ai + wv * CS, br + wv * CS, bi + wv * CS,
                  twr, twi, lane);
  for (int i = tid; i < 2048; i += 512) {
    const int row = i >> 3, c = i & 7;
    base[(row << 8) + c] = make_float2(ar[c * CS + row], ai[c * CS + row]);
  }
}

// ---------------------------------------------------------------------------
// FUSED spectral combine + inverse column FFT.  Reads full A (Hermitian
// mirror gathered from L2-hot A directly), computes
// hatv = -i*(X*kx+Y*ky)/rad (DC <- sumv), then inverse-FFTs the panel's 8
// columns and writes Bf. Saves one full 16MB pass + dispatch.
// ---------------------------------------------------------------------------
__global__ __launch_bounds__(512) void k_combine_invcol(const float2* __restrict__ A,
                                                        const float* __restrict__ sum,
                                                        float2* __restrict__ Bf)
{
  constexpr int CS = 260;
  __shared__ float ar[8 * CS], ai[8 * CS], br[8 * CS], bi[8 * CS];
  __shared__ float twr[128], twi[128];
  const int tid = threadIdx.x;
  const int lane = tid & 63;
  const int wv = tid >> 6;
  const int b = blockIdx.x >> 5;
  const int x0 = (blockIdx.x & 31) << 3;
  const float2* Ab = A + ((size_t)b << 16);

  for (int i = tid; i < 2048; i += 512) {
    const int ky = i >> 3, c = i & 7;
    const int kx = x0 + c;
    const float2 Zk = Ab[(ky << 8) + kx];
    const int ky2 = (256 - ky) & 255, kx2 = (256 - kx) & 255;
    const float2 Zm = Ab[(ky2 << 8) + kx2];
    const float Xr = 0.5f * (Zk.x + Zm.x), Xi = 0.5f * (Zk.y - Zm.y);
    const float Yr = 0.5f * (Zk.y + Zm.y), Yi = 0.5f * (Zm.x - Zk.x);
    const float fx = 0.25f * (float)(kx < 128 ? kx : kx - 256);
    const float fy = 0.25f * (float)(ky < 128 ? ky : ky - 256);
    const float kxv = TWO_PI * fx, kyv = TWO_PI * fy;
    float re, im;
    if ((ky | kx) == 0) {
      re = sum[0]; im = 0.0f;
    } else {
      const float rad = kxv * kxv + kyv * kyv;
      const float sr = Xr * kxv + Yr * kyv;
      const float si = Xi * kxv + Yi * kyv;
      re = si / rad; im = -sr / rad;       // -i*(sr+i*si)/rad
    }
    ar[c * CS + ky] = re;
    ai[c * CS + ky] = im;
  }
  for (int t = tid; t < 128; t += 512) {
    float s, c;
    sincosf((float)INV * (TWO_PI / 256.0f) * (float)t, &s, &c);
    twr[t] = c; twi[t] = s;
  }
  fft256_stockham(ar + wv * CS, ai + wv * CS, br + wv * CS, bi + wv * CS,
                  twr, twi, lane);
  float2* ob = Bf + ((size_t)b << 16) + x0;
  for (int i = tid; i < 2048; i += 512) {
    const int row = i >> 3, c = i & 7;
    ob[(row << 8) + c] = make_float2(ar[c * CS + row], ai[c * CS + row]);
  }
}

// ---------------------------------------------------------------------------
// Inverse ROW FFT fused with extraction: u = Re(.)/65536, ut = wtc*c.
// ---------------------------------------------------------------------------
__global__ __launch_bounds__(64) void k_inv_rows_extract(const float2* __restrict__ Bf,
                                                         const float* __restrict__ in,
                                                         float* __restrict__ u,
                                                         float* __restrict__ ut)
{
  __shared__ float ar[256], ai[256], br[256], bi[256], twr[128], twi[128];
  const int tid = threadIdx.x;
  const int row = blockIdx.x;            // b*256 + y
  const int b = row >> 8, y = row & 255;
  const float2* p = Bf + ((size_t)row << 8);
  for (int i = tid; i < 256; i += 64) { const float2 v = p[i]; ar[i] = v.x; ai[i] = v.y; }
  for (int t = tid; t < 128; t += 64) {
    float s, c;
    sincosf((float)INV * (TWO_PI / 256.0f) * (float)t, &s, &c);
    twr[t] = c; twi[t] = s;
  }
  fft256_stockham(ar, ai, br, bi, twr, twi, tid);
  const float* wtc = in + ((size_t)((b << 2) | 2) << 16) + (y << 8);
  const float* vc  = in + ((size_t)((b << 2) | 3) << 16) + (y << 8);
  float* uo  = u  + ((size_t)row << 8);
  float* uto = ut + ((size_t)row << 8);
  for (int i = tid; i < 256; i += 64) {
    uo[i]  = ar[i] * (1.0f / 65536.0f);
    uto[i] = wtc[i] * vc[i];
  }
}

// ---------------------------------------------------------------------------
// EIGHT fused velocity-Verlet steps, REGISTER-TILED.
// 256 threads = 16x16, each owning a 3x3 cell tile. ut/c2/lap live entirely
// in registers (fixed ownership); only u is exchanged through LDS, and only
// tile-edge cells (8 writes + 12 halo reads per thread per step).
// Validity margins (u-frame [m,50-m)): u_j valid m=j, ut_j valid m=j+1.
// After 8 steps: u_8 valid on [8,42)^2, ut_8 on [9,41)^2 = output tile.
// FINAL=1 additionally computes the energy components in-kernel and writes
// the 4-channel output directly (u neighbors at frame col/row 8 are valid;
// interior cells are bitwise identical across the blocks that compute them,
// since all fp expressions and inputs are identical).
// Barrier scheme: each step's edge-publish must be fenced from the PREVIOUS
// halo reads (loop-end barrier for j>=1; an explicit pre-loop barrier covers
// j=0 vs the lap(u_0) reads).
// LDS = 50*51 + 48*49 floats = 19608 B -> 4 blocks/CU -> 1024 blocks in one
// round. grid: 16*64 = 1024 blocks x 256 threads.
// ---------------------------------------------------------------------------
template <int FINAL>
__global__ __launch_bounds__(256, 4) void k_verlet8(const float* __restrict__ u_in,
                                                    const float* __restrict__ ut_in,
                                                    const float* __restrict__ in,
                                                    float* __restrict__ u_out,
                                                    float* __restrict__ ut_out,
                                                    float* __restrict__ out)
{
  __shared__ float su[50 * 51];     // u frame, halo 9, stride 51
  __shared__ float tmp[48 * 49];    // staging for ut, then c
  const int tid = threadIdx.x;
  const int b = blockIdx.x >> 6, t = blockIdx.x & 63;
  const int ty0 = (t >> 3) << 5, tx0 = (t & 7) << 5;  // tile origin (global)
  const int ty = tid >> 4, tx = tid & 15;             // 16x16 thread grid
  const int y0 = 1 + 3 * ty, x0 = 1 + 3 * tx;         // u-frame origin of 3x3
  const float* ub  = u_in  + ((size_t)b << 16);
  const float* utb = ut_in + ((size_t)b << 16);
  const float* vb  = in + ((size_t)((b << 2) | 3) << 16);

  // ---- stage u frame (halo 9), coalesced
  for (int i = tid; i < 2500; i += 256) {
    const int iy = i / 50, ix = i - iy * 50;
    const int gy = (ty0 + iy - 9) & 255, gx = (tx0 + ix - 9) & 255;
    su[iy * 51 + ix] = ub[(gy << 8) + gx];
  }
  // ---- stage ut on C (halo 8), coalesced, -> regs
  for (int i = tid; i < 2304; i += 256) {
    const int iy = i / 48, ix = i - iy * 48;
    const int gy = (ty0 + iy - 8) & 255, gx = (tx0 + ix - 8) & 255;
    tmp[iy * 49 + ix] = utb[(gy << 8) + gx];
  }
  __syncthreads();

  float uR[3][3], utR[3][3], c2R[3][3], laR[3][3];
#pragma unroll
  for (int r = 0; r < 3; ++r)
#pragma unroll
    for (int c = 0; c < 3; ++c) {
      uR[r][c]  = su[(y0 + r) * 51 + x0 + c];
      utR[r][c] = tmp[(3 * ty + r) * 49 + 3 * tx + c];
    }
  __syncthreads();
  // ---- stage c on C -> c2 regs (c2 = c*c, as reference)
  for (int i = tid; i < 2304; i += 256) {
    const int iy = i / 48, ix = i - iy * 48;
    const int gy = (ty0 + iy - 8) & 255, gx = (tx0 + ix - 8) & 255;
    tmp[iy * 49 + ix] = vb[(gy << 8) + gx];
  }
  __syncthreads();
#pragma unroll
  for (int r = 0; r < 3; ++r)
#pragma unroll
    for (int c = 0; c < 3; ++c) {
      const float cv = tmp[(3 * ty + r) * 49 + 3 * tx + c];
      c2R[r][c] = cv * cv;
    }

  float hN[3], hS[3], hW[3], hE[3];
  // halo loader: 12 LDS reads (neighbors' edge cells)
  auto load_halo = [&]() {
#pragma unroll
    for (int c = 0; c < 3; ++c) {
      hN[c] = su[(y0 - 1) * 51 + x0 + c];
      hS[c] = su[(y0 + 3) * 51 + x0 + c];
    }
#pragma unroll
    for (int r = 0; r < 3; ++r) {
      hW[r] = su[(y0 + r) * 51 + x0 - 1];
      hE[r] = su[(y0 + r) * 51 + x0 + 3];
    }
  };
  // lap at cell (r,c) in reference fp order: ((((L-2v)+R)+U)-2v)+D)*INV_DX2
  auto lap_cell = [&](int r, int c) -> float {
    const float v = uR[r][c];
    const float L = (c == 0) ? hW[r] : uR[r][c - 1];
    const float R = (c == 2) ? hE[r] : uR[r][c + 1];
    const float U = (r == 0) ? hN[c] : uR[r - 1][c];
    const float D = (r == 2) ? hS[c] : uR[r + 1][c];
    const float t2 = 2.0f * v;
    return (((((L - t2) + R) + U) - t2) + D) * INV_DX2;
  };

  // ---- lap(u_0)
  load_halo();
#pragma unroll
  for (int r = 0; r < 3; ++r)
#pragma unroll
    for (int c = 0; c < 3; ++c) laR[r][c] = lap_cell(r, c);
  // RACE FIX: fence the lap(u_0) halo reads (above) from step 0's edge
  // publishes (below) — for j>=1 the loop-end barrier provides this.
  __syncthreads();

  // ---- 8 fused steps
  for (int j = 0; j < 8; ++j) {
    // u_new = (u + dt*ut) + ((hdt2*c2)*lap0)    [registers only]
#pragma unroll
    for (int r = 0; r < 3; ++r)
#pragma unroll
      for (int c = 0; c < 3; ++c)
        uR[r][c] = (uR[r][c] + DTf * utR[r][c]) + (HDT2f * c2R[r][c]) * laR[r][c];
    // publish the 8 edge cells
    su[(y0    ) * 51 + x0    ] = uR[0][0];
    su[(y0    ) * 51 + x0 + 1] = uR[0][1];
    su[(y0    ) * 51 + x0 + 2] = uR[0][2];
    su[(y0 + 1) * 51 + x0    ] = uR[1][0];
    su[(y0 + 1) * 51 + x0 + 2] = uR[1][2];
    su[(y0 + 2) * 51 + x0    ] = uR[2][0];
    su[(y0 + 2) * 51 + x0 + 1] = uR[2][1];
    su[(y0 + 2) * 51 + x0 + 2] = uR[2][2];
    __syncthreads();
    load_halo();
    // lap1; ut += (hdt*c2)*(lap0+lap1); lap0 <- lap1
#pragma unroll
    for (int r = 0; r < 3; ++r)
#pragma unroll
      for (int c = 0; c < 3; ++c) {
        const float ln = lap_cell(r, c);
        utR[r][c] = utR[r][c] + (HDTf * c2R[r][c]) * (laR[r][c] + ln);
        laR[r][c] = ln;
      }
    __syncthreads();   // protect next step's edge writes from this step's reads
  }

  // ---- stage full u_8 into su (all 9 cells), then epilogue
#pragma unroll
  for (int r = 0; r < 3; ++r)
#pragma unroll
    for (int c = 0; c < 3; ++c) su[(y0 + r) * 51 + x0 + c] = uR[r][c];
  __syncthreads();

  if (FINAL) {
    // energy components from u_8 (valid on frame [8,42)) + ut_8 (tile)
    float wxv[4], wyv[4];
#pragma unroll
    for (int k = 0; k < 4; ++k) {
      const int i = tid + (k << 8);
      const int oy = i >> 5, ox = i & 31;
      const float uc = su[(9 + oy) * 51 + 9 + ox];
      wxv[k] = (tx0 + ox == 0) ? 0.0f : (uc - su[(9 + oy) * 51 + 8 + ox]) * INV_DX;
      wyv[k] = (ty0 + oy == 0) ? 0.0f : (uc - su[(8 + oy) * 51 + 9 + ox]) * INV_DX;
    }
    __syncthreads();
#pragma unroll
    for (int r = 0; r < 3; ++r)
#pragma unroll
      for (int c = 0; c < 3; ++c) su[(y0 + r) * 51 + x0 + c] = utR[r][c];
    __syncthreads();
#pragma unroll
    for (int k = 0; k < 4; ++k) {
      const int i = tid + (k << 8);
      const int oy = i >> 5, ox = i & 31;
      const int g = ((ty0 + oy) << 8) + (tx0 + ox);
      const float utv = su[(9 + oy) * 51 + 9 + ox];
      const float cv  = vb[g];
      out[((size_t)(b << 2) << 16) + g]       = wxv[k];
      out[((size_t)((b << 2) | 1) << 16) + g] = wyv[k];
      out[((size_t)((b << 2) | 2) << 16) + g] = utv / cv;
      out[((size_t)((b << 2) | 3) << 16) + g] = cv;
    }
  } else {
    float* uob  = u_out  + ((size_t)b << 16);
    float* utob = ut_out + ((size_t)b << 16);
    for (int i = tid; i < 1024; i += 256) {
      const int oy = i >> 5, ox = i & 31;
      uob[((ty0 + oy) << 8) + tx0 + ox] = su[(9 + oy) * 51 + 9 + ox];
    }
    __syncthreads();
#pragma unroll
    for (int r = 0; r < 3; ++r)
#pragma unroll
      for (int c = 0; c < 3; ++c) su[(y0 + r) * 51 + x0 + c] = utR[r][c];
    __syncthreads();
    for (int i = tid; i < 1024; i += 256) {
      const int oy = i >> 5, ox = i & 31;
      utob[((ty0 + oy) << 8) + tx0 + ox] = su[(9 + oy) * 51 + 9 + ox];
    }
  }
}

// ---------------------------------------------------------------------------
// Buffer plan — ws requirement: 8 MB. Lifetimes:
//   ws[0:4)       : sumv (memset -> read in combine_invcol; dead before u0)
//   ws[0:8MB)     : u0/ut0 (written by EVEN verlet steps; read by odd+final)
//   d_out[0:8MB)  : A (fwd spectrum; dead after combine), then u1/ut1
//                   (written by extract + ODD steps s<7; dead after s=6 read)
//   d_out[8:16MB) : Bf (inv spectrum; dead after extract)
//   d_out (full)  : final 4-channel output, written by the FINAL verlet
//                   launch, which reads ONLY ws + in -> no aliasing hazard.
// Pipeline: memset -> rowFFT+pack+sum -> fwd colFFT -> combine+inv colFFT
//   -> inv rowFFT+extract(->d_out lo) -> verlet x8 (even: d_out->ws,
//   odd: ws->d_out; s=7 FINAL: ws->out). 13 dispatches total.
// ---------------------------------------------------------------------------
extern "C" void kernel_launch(void* const* d_in, const int* in_sizes, int n_in,
                              void* d_out, int out_size, void* d_ws, size_t ws_size,
                              hipStream_t stream)
{
  const float* in = (const float*)d_in[0];
  float* out = (float*)d_out;
  char* ws = (char*)d_ws;

  float2* A   = (float2*)d_out;                 // d_out[0:8MB)
  float*  u1  = (float*)d_out;                  // same 8MB, after A dies
  float*  ut1 = u1 + NTOT;
  float2* Bf  = (float2*)((float*)d_out + 2 * NTOT);   // d_out[8:16MB)

  float*  sum = (float*)ws;                     // ws[0:4), dead before u0
  float*  u0  = (float*)ws;                     // ws[0:8MB)
  float*  ut0 = u0 + NTOT;

  hipMemsetAsync(sum, 0, sizeof(float), stream);

  k_fwd_rows_pack<<<NBATCH * 256, 64, 0, stream>>>(in, A, sum);
  k_fft_cols_panel_fwd<<<NBATCH * 32, 512, 0, stream>>>(A);
  k_combine_invcol<<<NBATCH * 32, 512, 0, stream>>>(A, sum, Bf);
  k_inv_rows_extract<<<NBATCH * 256, 64, 0, stream>>>(Bf, in, u1, ut1);

  // 64 Verlet steps = 8 launches x 8 fused steps.
  // even s: (u1,ut1)[d_out] -> (u0,ut0)[ws]; odd s<7: ws -> d_out;
  // s=7 (FINAL): ws -> out (fused energy + output assembly).
  for (int s = 0; s < 7; ++s) {
    if (s & 1) k_verlet8<0><<<NBATCH * 64, 256, 0, stream>>>(u0, ut0, in, u1, ut1, out);
    else       k_verlet8<0><<<NBATCH * 64, 256, 0, stream>>>(u1, ut1, in, u0, ut0, out);
  }
  k_verlet8<1><<<NBATCH * 64, 256, 0, stream>>>(u0, ut0, in, u1, ut1, out);
}

// Round 9
// 259.623 us; speedup vs baseline: 2.5301x; 1.1834x over previous
//
#include <hip/hip_runtime.h>

// Problem constants (fixed by reference): B=16, H=W=256, dx=2/128, dt=1e-3, nt=64
#define NBATCH 16
#define NPIX   65536             // 256*256
#define NTOT   (NBATCH * NPIX)   // 1,048,576

constexpr float DTf    = 0.001f;                         // dt
constexpr float HDTf   = 0.0005f;                        // (float)(0.5*dt)
constexpr float HDT2f  = 5.0000000000000004e-07f;        // (float)(0.5*dt*dt)
constexpr float INV_DX  = 64.0f;                         // 1/dx (exact pow2)
constexpr float INV_DX2 = 4096.0f;                       // 1/dx^2 (exact pow2)
constexpr float TWO_PI  = 6.28318530717958647692f;

constexpr int FWD = -1;
constexpr int INV =  1;

// ---------------------------------------------------------------------------
// 256-point Stockham autosort FFT in LDS (DIF, twiddle-after-subtract).
// One wave per transform; natural order in/out; result ends in ar/ai.
// Safe in multi-wave blocks (all waves run identical stage counts).
// ---------------------------------------------------------------------------
__device__ __forceinline__ void fft256_stockham(float* ar, float* ai,
                                                float* br, float* bi,
                                                const float* twr, const float* twi,
                                                int lane)
{
  float *xr = ar, *xi = ai, *yr = br, *yi = bi;
#pragma unroll
  for (int s = 0; s < 8; ++s) {
    const int m = 1 << s;
    __syncthreads();
#pragma unroll
    for (int q = 0; q < 2; ++q) {
      const int b  = lane + (q << 6);       // butterfly id in [0,128)
      const int jm = b & ~(m - 1);          // j*m = twiddle index
      const float wr = twr[jm], wi = twi[jm];
      const float c0r = xr[b],       c0i = xi[b];
      const float c1r = xr[b + 128], c1i = xi[b + 128];
      const int i0 = b + jm, i1 = i0 + m;
      yr[i0] = c0r + c1r;
      yi[i0] = c0i + c1i;
      const float dr = c0r - c1r, di = c0i - c1i;
      yr[i1] = wr * dr - wi * di;
      yi[i1] = wr * di + wi * dr;
    }
    float* t;
    t = xr; xr = yr; yr = t;
    t = xi; xi = yi; yi = t;
  }
  __syncthreads();   // 8 swaps -> result back in ar/ai
}

// ---------------------------------------------------------------------------
// Forward ROW FFT, 8 rows per block (512 thr = 8 waves; wave w owns row w of
// the block's row range), fused with packing z = wx + i*wy and the sum(wx)
// reduction (block tree -> one atomicAdd). Per-wave LDS segment stride 256:
// lane banks = e&31, 2 lanes/bank (free). LDS ~33 KB -> 4 blocks/CU ->
// 32 waves/CU. grid: 4096/8 = 512 blocks.
// ---------------------------------------------------------------------------
__global__ __launch_bounds__(512) void k_fwd_rows_pack(const float* __restrict__ in,
                                                       float2* __restrict__ A,
                                                       float* __restrict__ sum)
{
  __shared__ float ar[8 * 256], ai[8 * 256], br[8 * 256], bi[8 * 256];
  __shared__ float twr[128], twi[128];
  __shared__ float part[8];
  const int tid = threadIdx.x;
  const int lane = tid & 63;
  const int wv = tid >> 6;
  const int row0 = blockIdx.x << 3;      // first global row of this block

  float acc = 0.0f;
  for (int i = tid; i < 2048; i += 512) {
    const int r = i >> 8, e = i & 255;
    const int row = row0 + r;
    const int b = row >> 8, y = row & 255;
    const float vx = in[((size_t)(b << 2) << 16) + (y << 8) + e];
    const float vy = in[((size_t)((b << 2) | 1) << 16) + (y << 8) + e];
    ar[(r << 8) + e] = vx; acc += vx;
    ai[(r << 8) + e] = vy;
  }
  for (int t = tid; t < 128; t += 512) {
    float s, c;
    sincosf((float)FWD * (TWO_PI / 256.0f) * (float)t, &s, &c);
    twr[t] = c; twi[t] = s;
  }
#pragma unroll
  for (int o = 32; o > 0; o >>= 1) acc += __shfl_down(acc, o);
  if (lane == 0) part[wv] = acc;
  __syncthreads();
  if (tid == 0) {
    float s = part[0];
#pragma unroll
    for (int w = 1; w < 8; ++w) s += part[w];
    atomicAdd(sum, s);
  }

  fft256_stockham(ar + (wv << 8), ai + (wv << 8), br + (wv << 8), bi + (wv << 8),
                  twr, twi, lane);

  for (int i = tid; i < 2048; i += 512) {
    const int r = i >> 8, e = i & 255;
    A[((size_t)(row0 + r) << 8) + e] = make_float2(ar[(r << 8) + e], ai[(r << 8) + e]);
  }
}

// ---------------------------------------------------------------------------
// In-place forward column FFT, 8-column panel per block. 512 thr = 8 waves.
// LDS per-column stride 260 -> <=2 lanes/bank (free).
// ---------------------------------------------------------------------------
__global__ __launch_bounds__(512) void k_fft_cols_panel_fwd(float2* __restrict__ X)
{
  constexpr int CS = 260;
  __shared__ float ar[8 * CS], ai[8 * CS], br[8 * CS], bi[8 * CS];
  __shared__ float twr[128], twi[128];
  const int tid = threadIdx.x;
  const int lane = tid & 63;
  const int wv = tid >> 6;
  const int b = blockIdx.x >> 5;
  const int x0 = (blockIdx.x & 31) << 3;
  float2* base = X + ((size_t)b << 16) + x0;

  for (int i = tid; i < 2048; i += 512) {
    const int row = i >> 3, c = i & 7;
    const float2 v = base[(row << 8) + c];
    ar[c * CS + row] = v.x;
    ai[c * CS + row] = v.y;
  }
  for (int t = tid; t < 128; t += 512) {
    float s, c;
    sincosf((float)FWD * (TWO_PI / 256.0f) * (float)t, &s, &c);
    twr[t] = c; twi[t] = s;
  }
  fft256_stockham(ar + wv * CS, ai + wv * CS, br + wv * CS, bi + wv * CS,
                  twr, twi, lane);
  for (int i = tid; i < 2048; i += 512) {
    const int row = i >> 3, c = i & 7;
    base[(row << 8) + c] = make_float2(ar[c * CS + row], ai[c * CS + row]);
  }
}

// ---------------------------------------------------------------------------
// FUSED spectral combine + inverse column FFT.  Reads full A (Hermitian
// mirror gathered from L2-hot A directly), computes
// hatv = -i*(X*kx+Y*ky)/rad (DC <- sumv), then inverse-FFTs the panel's 8
// columns and writes Bf. Saves one full 16MB pass + dispatch.
// ---------------------------------------------------------------------------
__global__ __launch_bounds__(512) void k_combine_invcol(const float2* __restrict__ A,
                                                        const float* __restrict__ sum,
                                                        float2* __restrict__ Bf)
{
  constexpr int CS = 260;
  __shared__ float ar[8 * CS], ai[8 * CS], br[8 * CS], bi[8 * CS];
  __shared__ float twr[128], twi[128];
  const int tid = threadIdx.x;
  const int lane = tid & 63;
  const int wv = tid >> 6;
  const int b = blockIdx.x >> 5;
  const int x0 = (blockIdx.x & 31) << 3;
  const float2* Ab = A + ((size_t)b << 16);

  for (int i = tid; i < 2048; i += 512) {
    const int ky = i >> 3, c = i & 7;
    const int kx = x0 + c;
    const float2 Zk = Ab[(ky << 8) + kx];
    const int ky2 = (256 - ky) & 255, kx2 = (256 - kx) & 255;
    const float2 Zm = Ab[(ky2 << 8) + kx2];
    const float Xr = 0.5f * (Zk.x + Zm.x), Xi = 0.5f * (Zk.y - Zm.y);
    const float Yr = 0.5f * (Zk.y + Zm.y), Yi = 0.5f * (Zm.x - Zk.x);
    const float fx = 0.25f * (float)(kx < 128 ? kx : kx - 256);
    const float fy = 0.25f * (float)(ky < 128 ? ky : ky - 256);
    const float kxv = TWO_PI * fx, kyv = TWO_PI * fy;
    float re, im;
    if ((ky | kx) == 0) {
      re = sum[0]; im = 0.0f;
    } else {
      const float rad = kxv * kxv + kyv * kyv;
      const float sr = Xr * kxv + Yr * kyv;
      const float si = Xi * kxv + Yi * kyv;
      re = si / rad; im = -sr / rad;       // -i*(sr+i*si)/rad
    }
    ar[c * CS + ky] = re;
    ai[c * CS + ky] = im;
  }
  for (int t = tid; t < 128; t += 512) {
    float s, c;
    sincosf((float)INV * (TWO_PI / 256.0f) * (float)t, &s, &c);
    twr[t] = c; twi[t] = s;
  }
  fft256_stockham(ar + wv * CS, ai + wv * CS, br + wv * CS, bi + wv * CS,
                  twr, twi, lane);
  float2* ob = Bf + ((size_t)b << 16) + x0;
  for (int i = tid; i < 2048; i += 512) {
    const int row = i >> 3, c = i & 7;
    ob[(row << 8) + c] = make_float2(ar[c * CS + row], ai[c * CS + row]);
  }
}

// ---------------------------------------------------------------------------
// Inverse ROW FFT, 8 rows per block (same structure as k_fwd_rows_pack),
// fused with extraction: u = Re(.)/65536, ut = wtc*c. grid: 512 blocks.
// ---------------------------------------------------------------------------
__global__ __launch_bounds__(512) void k_inv_rows_extract(const float2* __restrict__ Bf,
                                                          const float* __restrict__ in,
                                                          float* __restrict__ u,
                                                          float* __restrict__ ut)
{
  __shared__ float ar[8 * 256], ai[8 * 256], br[8 * 256], bi[8 * 256];
  __shared__ float twr[128], twi[128];
  const int tid = threadIdx.x;
  const int lane = tid & 63;
  const int wv = tid >> 6;
  const int row0 = blockIdx.x << 3;

  for (int i = tid; i < 2048; i += 512) {
    const int r = i >> 8, e = i & 255;
    const float2 v = Bf[((size_t)(row0 + r) << 8) + e];
    ar[(r << 8) + e] = v.x;
    ai[(r << 8) + e] = v.y;
  }
  for (int t = tid; t < 128; t += 512) {
    float s, c;
    sincosf((float)INV * (TWO_PI / 256.0f) * (float)t, &s, &c);
    twr[t] = c; twi[t] = s;
  }
  fft256_stockham(ar + (wv << 8), ai + (wv << 8), br + (wv << 8), bi + (wv << 8),
                  twr, twi, lane);

  for (int i = tid; i < 2048; i += 512) {
    const int r = i >> 8, e = i & 255;
    const int row = row0 + r;
    const int b = row >> 8, y = row & 255;
    const float wtc = in[((size_t)((b << 2) | 2) << 16) + (y << 8) + e];
    const float vc  = in[((size_t)((b << 2) | 3) << 16) + (y << 8) + e];
    u [((size_t)row << 8) + e] = ar[(r << 8) + e] * (1.0f / 65536.0f);
    ut[((size_t)row << 8) + e] = wtc * vc;
  }
}

// ---------------------------------------------------------------------------
// EIGHT fused velocity-Verlet steps, REGISTER-TILED.
// 256 threads = 16x16, each owning a 3x3 cell tile. ut/c2/lap live entirely
// in registers (fixed ownership); only u is exchanged through LDS, and only
// tile-edge cells (8 writes + 12 halo reads per thread per step).
// Validity margins (u-frame [m,50-m)): u_j valid m=j, ut_j valid m=j+1.
// After 8 steps: u_8 valid on [8,42)^2, ut_8 on [9,41)^2 = output tile.
// FINAL=1 additionally computes the energy components in-kernel and writes
// the 4-channel output directly. Barrier scheme: publish -> barrier ->
// halo-read -> barrier per step, plus a pre-loop fence for j=0.
// LDS = 50*51 + 48*49 floats = 19608 B -> 4 blocks/CU -> 1024 blocks in one
// round. grid: 16*64 = 1024 blocks x 256 threads.
// ---------------------------------------------------------------------------
template <int FINAL>
__global__ __launch_bounds__(256, 4) void k_verlet8(const float* __restrict__ u_in,
                                                    const float* __restrict__ ut_in,
                                                    const float* __restrict__ in,
                                                    float* __restrict__ u_out,
                                                    float* __restrict__ ut_out,
                                                    float* __restrict__ out)
{
  __shared__ float su[50 * 51];     // u frame, halo 9, stride 51
  __shared__ float tmp[48 * 49];    // staging for ut, then c
  const int tid = threadIdx.x;
  const int b = blockIdx.x >> 6, t = blockIdx.x & 63;
  const int ty0 = (t >> 3) << 5, tx0 = (t & 7) << 5;  // tile origin (global)
  const int ty = tid >> 4, tx = tid & 15;             // 16x16 thread grid
  const int y0 = 1 + 3 * ty, x0 = 1 + 3 * tx;         // u-frame origin of 3x3
  const float* ub  = u_in  + ((size_t)b << 16);
  const float* utb = ut_in + ((size_t)b << 16);
  const float* vb  = in + ((size_t)((b << 2) | 3) << 16);

  // ---- stage u frame (halo 9), coalesced
  for (int i = tid; i < 2500; i += 256) {
    const int iy = i / 50, ix = i - iy * 50;
    const int gy = (ty0 + iy - 9) & 255, gx = (tx0 + ix - 9) & 255;
    su[iy * 51 + ix] = ub[(gy << 8) + gx];
  }
  // ---- stage ut on C (halo 8), coalesced, -> regs
  for (int i = tid; i < 2304; i += 256) {
    const int iy = i / 48, ix = i - iy * 48;
    const int gy = (ty0 + iy - 8) & 255, gx = (tx0 + ix - 8) & 255;
    tmp[iy * 49 + ix] = utb[(gy << 8) + gx];
  }
  __syncthreads();

  float uR[3][3], utR[3][3], c2R[3][3], laR[3][3];
#pragma unroll
  for (int r = 0; r < 3; ++r)
#pragma unroll
    for (int c = 0; c < 3; ++c) {
      uR[r][c]  = su[(y0 + r) * 51 + x0 + c];
      utR[r][c] = tmp[(3 * ty + r) * 49 + 3 * tx + c];
    }
  __syncthreads();
  // ---- stage c on C -> c2 regs (c2 = c*c, as reference)
  for (int i = tid; i < 2304; i += 256) {
    const int iy = i / 48, ix = i - iy * 48;
    const int gy = (ty0 + iy - 8) & 255, gx = (tx0 + ix - 8) & 255;
    tmp[iy * 49 + ix] = vb[(gy << 8) + gx];
  }
  __syncthreads();
#pragma unroll
  for (int r = 0; r < 3; ++r)
#pragma unroll
    for (int c = 0; c < 3; ++c) {
      const float cv = tmp[(3 * ty + r) * 49 + 3 * tx + c];
      c2R[r][c] = cv * cv;
    }

  float hN[3], hS[3], hW[3], hE[3];
  // halo loader: 12 LDS reads (neighbors' edge cells)
  auto load_halo = [&]() {
#pragma unroll
    for (int c = 0; c < 3; ++c) {
      hN[c] = su[(y0 - 1) * 51 + x0 + c];
      hS[c] = su[(y0 + 3) * 51 + x0 + c];
    }
#pragma unroll
    for (int r = 0; r < 3; ++r) {
      hW[r] = su[(y0 + r) * 51 + x0 - 1];
      hE[r] = su[(y0 + r) * 51 + x0 + 3];
    }
  };
  // lap at cell (r,c) in reference fp order: ((((L-2v)+R)+U)-2v)+D)*INV_DX2
  auto lap_cell = [&](int r, int c) -> float {
    const float v = uR[r][c];
    const float L = (c == 0) ? hW[r] : uR[r][c - 1];
    const float R = (c == 2) ? hE[r] : uR[r][c + 1];
    const float U = (r == 0) ? hN[c] : uR[r - 1][c];
    const float D = (r == 2) ? hS[c] : uR[r + 1][c];
    const float t2 = 2.0f * v;
    return (((((L - t2) + R) + U) - t2) + D) * INV_DX2;
  };

  // ---- lap(u_0)
  load_halo();
#pragma unroll
  for (int r = 0; r < 3; ++r)
#pragma unroll
    for (int c = 0; c < 3; ++c) laR[r][c] = lap_cell(r, c);
  // Fence the lap(u_0) halo reads from step 0's edge publishes.
  __syncthreads();

  // ---- 8 fused steps
  for (int j = 0; j < 8; ++j) {
    // u_new = (u + dt*ut) + ((hdt2*c2)*lap0)    [registers only]
#pragma unroll
    for (int r = 0; r < 3; ++r)
#pragma unroll
      for (int c = 0; c < 3; ++c)
        uR[r][c] = (uR[r][c] + DTf * utR[r][c]) + (HDT2f * c2R[r][c]) * laR[r][c];
    // publish the 8 edge cells
    su[(y0    ) * 51 + x0    ] = uR[0][0];
    su[(y0    ) * 51 + x0 + 1] = uR[0][1];
    su[(y0    ) * 51 + x0 + 2] = uR[0][2];
    su[(y0 + 1) * 51 + x0    ] = uR[1][0];
    su[(y0 + 1) * 51 + x0 + 2] = uR[1][2];
    su[(y0 + 2) * 51 + x0    ] = uR[2][0];
    su[(y0 + 2) * 51 + x0 + 1] = uR[2][1];
    su[(y0 + 2) * 51 + x0 + 2] = uR[2][2];
    __syncthreads();
    load_halo();
    // lap1; ut += (hdt*c2)*(lap0+lap1); lap0 <- lap1
#pragma unroll
    for (int r = 0; r < 3; ++r)
#pragma unroll
      for (int c = 0; c < 3; ++c) {
        const float ln = lap_cell(r, c);
        utR[r][c] = utR[r][c] + (HDTf * c2R[r][c]) * (laR[r][c] + ln);
        laR[r][c] = ln;
      }
    __syncthreads();   // protect next step's edge writes from this step's reads
  }

  // ---- stage full u_8 into su (all 9 cells), then epilogue
#pragma unroll
  for (int r = 0; r < 3; ++r)
#pragma unroll
    for (int c = 0; c < 3; ++c) su[(y0 + r) * 51 + x0 + c] = uR[r][c];
  __syncthreads();

  if (FINAL) {
    // energy components from u_8 (valid on frame [8,42)) + ut_8 (tile)
    float wxv[4], wyv[4];
#pragma unroll
    for (int k = 0; k < 4; ++k) {
      const int i = tid + (k << 8);
      const int oy = i >> 5, ox = i & 31;
      const float uc = su[(9 + oy) * 51 + 9 + ox];
      wxv[k] = (tx0 + ox == 0) ? 0.0f : (uc - su[(9 + oy) * 51 + 8 + ox]) * INV_DX;
      wyv[k] = (ty0 + oy == 0) ? 0.0f : (uc - su[(8 + oy) * 51 + 9 + ox]) * INV_DX;
    }
    __syncthreads();
#pragma unroll
    for (int r = 0; r < 3; ++r)
#pragma unroll
      for (int c = 0; c < 3; ++c) su[(y0 + r) * 51 + x0 + c] = utR[r][c];
    __syncthreads();
#pragma unroll
    for (int k = 0; k < 4; ++k) {
      const int i = tid + (k << 8);
      const int oy = i >> 5, ox = i & 31;
      const int g = ((ty0 + oy) << 8) + (tx0 + ox);
      const float utv = su[(9 + oy) * 51 + 9 + ox];
      const float cv  = vb[g];
      out[((size_t)(b << 2) << 16) + g]       = wxv[k];
      out[((size_t)((b << 2) | 1) << 16) + g] = wyv[k];
      out[((size_t)((b << 2) | 2) << 16) + g] = utv / cv;
      out[((size_t)((b << 2) | 3) << 16) + g] = cv;
    }
  } else {
    float* uob  = u_out  + ((size_t)b << 16);
    float* utob = ut_out + ((size_t)b << 16);
    for (int i = tid; i < 1024; i += 256) {
      const int oy = i >> 5, ox = i & 31;
      uob[((ty0 + oy) << 8) + tx0 + ox] = su[(9 + oy) * 51 + 9 + ox];
    }
    __syncthreads();
#pragma unroll
    for (int r = 0; r < 3; ++r)
#pragma unroll
      for (int c = 0; c < 3; ++c) su[(y0 + r) * 51 + x0 + c] = utR[r][c];
    __syncthreads();
    for (int i = tid; i < 1024; i += 256) {
      const int oy = i >> 5, ox = i & 31;
      utob[((ty0 + oy) << 8) + tx0 + ox] = su[(9 + oy) * 51 + 9 + ox];
    }
  }
}

// ---------------------------------------------------------------------------
// Buffer plan — ws requirement: 8 MB. Lifetimes:
//   ws[0:4)       : sumv (memset -> read in combine_invcol; dead before u0)
//   ws[0:8MB)     : u0/ut0 (written by EVEN verlet steps; read by odd+final)
//   d_out[0:8MB)  : A (fwd spectrum; dead after combine), then u1/ut1
//                   (written by extract + ODD steps s<7; dead after s=6 read)
//   d_out[8:16MB) : Bf (inv spectrum; dead after extract)
//   d_out (full)  : final 4-channel output, written by the FINAL verlet
//                   launch, which reads ONLY ws + in -> no aliasing hazard.
// Pipeline: memset -> rowFFT+pack+sum -> fwd colFFT -> combine+inv colFFT
//   -> inv rowFFT+extract(->d_out lo) -> verlet x8 (even: d_out->ws,
//   odd: ws->d_out; s=7 FINAL: ws->out). 13 dispatches total.
// ---------------------------------------------------------------------------
extern "C" void kernel_launch(void* const* d_in, const int* in_sizes, int n_in,
                              void* d_out, int out_size, void* d_ws, size_t ws_size,
                              hipStream_t stream)
{
  const float* in = (const float*)d_in[0];
  float* out = (float*)d_out;
  char* ws = (char*)d_ws;

  float2* A   = (float2*)d_out;                 // d_out[0:8MB)
  float*  u1  = (float*)d_out;                  // same 8MB, after A dies
  float*  ut1 = u1 + NTOT;
  float2* Bf  = (float2*)((float*)d_out + 2 * NTOT);   // d_out[8:16MB)

  float*  sum = (float*)ws;                     // ws[0:4), dead before u0
  float*  u0  = (float*)ws;                     // ws[0:8MB)
  float*  ut0 = u0 + NTOT;

  hipMemsetAsync(sum, 0, sizeof(float), stream);

  k_fwd_rows_pack<<<NBATCH * 32, 512, 0, stream>>>(in, A, sum);
  k_fft_cols_panel_fwd<<<NBATCH * 32, 512, 0, stream>>>(A);
  k_combine_invcol<<<NBATCH * 32, 512, 0, stream>>>(A, sum, Bf);
  k_inv_rows_extract<<<NBATCH * 32, 512, 0, stream>>>(Bf, in, u1, ut1);

  // 64 Verlet steps = 8 launches x 8 fused steps.
  // even s: (u1,ut1)[d_out] -> (u0,ut0)[ws]; odd s<7: ws -> d_out;
  // s=7 (FINAL): ws -> out (fused energy + output assembly).
  for (int s = 0; s < 7; ++s) {
    if (s & 1) k_verlet8<0><<<NBATCH * 64, 256, 0, stream>>>(u0, ut0, in, u1, ut1, out);
    else       k_verlet8<0><<<NBATCH * 64, 256, 0, stream>>>(u1, ut1, in, u0, ut0, out);
  }
  k_verlet8<1><<<NBATCH * 64, 256, 0, stream>>>(u0, ut0, in, u1, ut1, out);
}

// Round 11
// 255.687 us; speedup vs baseline: 2.5690x; 1.0154x over previous
//
#include <hip/hip_runtime.h>

// Problem constants (fixed by reference): B=16, H=W=256, dx=2/128, dt=1e-3, nt=64
#define NBATCH 16
#define NPIX   65536             // 256*256
#define NTOT   (NBATCH * NPIX)   // 1,048,576

constexpr float DTf    = 0.001f;                         // dt
constexpr float HDTf   = 0.0005f;                        // (float)(0.5*dt)
constexpr float HDT2f  = 5.0000000000000004e-07f;        // (float)(0.5*dt*dt)
constexpr float INV_DX  = 64.0f;                         // 1/dx (exact pow2)
constexpr float INV_DX2 = 4096.0f;                       // 1/dx^2 (exact pow2)
constexpr float TWO_PI  = 6.28318530717958647692f;

constexpr int FWD = -1;
constexpr int INV =  1;

// ---------------------------------------------------------------------------
// 256-point Stockham autosort FFT in LDS (DIF, twiddle-after-subtract).
// One wave per transform; natural order in/out; result ends in ar/ai.
// Safe in multi-wave blocks (all waves run identical stage counts); safe
// when two waves redundantly transform the SAME slot (identical writes,
// barrier-aligned stages).
// ---------------------------------------------------------------------------
__device__ __forceinline__ void fft256_stockham(float* ar, float* ai,
                                                float* br, float* bi,
                                                const float* twr, const float* twi,
                                                int lane)
{
  float *xr = ar, *xi = ai, *yr = br, *yi = bi;
#pragma unroll
  for (int s = 0; s < 8; ++s) {
    const int m = 1 << s;
    __syncthreads();
#pragma unroll
    for (int q = 0; q < 2; ++q) {
      const int b  = lane + (q << 6);       // butterfly id in [0,128)
      const int jm = b & ~(m - 1);          // j*m = twiddle index
      const float wr = twr[jm], wi = twi[jm];
      const float c0r = xr[b],       c0i = xi[b];
      const float c1r = xr[b + 128], c1i = xi[b + 128];
      const int i0 = b + jm, i1 = i0 + m;
      yr[i0] = c0r + c1r;
      yi[i0] = c0i + c1i;
      const float dr = c0r - c1r, di = c0i - c1i;
      yr[i1] = wr * dr - wi * di;
      yi[i1] = wr * di + wi * dr;
    }
    float* t;
    t = xr; xr = yr; yr = t;
    t = xi; xi = yi; yi = t;
  }
  __syncthreads();   // 8 swaps -> result back in ar/ai
}

// ---------------------------------------------------------------------------
// Forward ROW FFT, 8 rows per block (512 thr = 8 waves), fused with packing
// z = wx + i*wy and the sum(wx) reduction. grid: 512 blocks.
// ---------------------------------------------------------------------------
__global__ __launch_bounds__(512) void k_fwd_rows_pack(const float* __restrict__ in,
                                                       float2* __restrict__ A,
                                                       float* __restrict__ sum)
{
  __shared__ float ar[8 * 256], ai[8 * 256], br[8 * 256], bi[8 * 256];
  __shared__ float twr[128], twi[128];
  __shared__ float part[8];
  const int tid = threadIdx.x;
  const int lane = tid & 63;
  const int wv = tid >> 6;
  const int row0 = blockIdx.x << 3;      // first global row of this block

  float acc = 0.0f;
  for (int i = tid; i < 2048; i += 512) {
    const int r = i >> 8, e = i & 255;
    const int row = row0 + r;
    const int b = row >> 8, y = row & 255;
    const float vx = in[((size_t)(b << 2) << 16) + (y << 8) + e];
    const float vy = in[((size_t)((b << 2) | 1) << 16) + (y << 8) + e];
    ar[(r << 8) + e] = vx; acc += vx;
    ai[(r << 8) + e] = vy;
  }
  for (int t = tid; t < 128; t += 512) {
    float s, c;
    sincosf((float)FWD * (TWO_PI / 256.0f) * (float)t, &s, &c);
    twr[t] = c; twi[t] = s;
  }
#pragma unroll
  for (int o = 32; o > 0; o >>= 1) acc += __shfl_down(acc, o);
  if (lane == 0) part[wv] = acc;
  __syncthreads();
  if (tid == 0) {
    float s = part[0];
#pragma unroll
    for (int w = 1; w < 8; ++w) s += part[w];
    atomicAdd(sum, s);
  }

  fft256_stockham(ar + (wv << 8), ai + (wv << 8), br + (wv << 8), bi + (wv << 8),
                  twr, twi, lane);

  for (int i = tid; i < 2048; i += 512) {
    const int r = i >> 8, e = i & 255;
    A[((size_t)(row0 + r) << 8) + e] = make_float2(ar[(r << 8) + e], ai[(r << 8) + e]);
  }
}

// ---------------------------------------------------------------------------
// FULLY FUSED column phase: fwd col FFT + spectral combine + inverse col FFT
// in ONE kernel. Block = 1024 threads (16 waves) on an 8-column panel PLUS
// its Hermitian-mirror panel (slots 8..15 hold columns (256-kx)&255).
// wave w fwd-FFTs slot w; combine reads Zk = slot c @ ky, Zm = slot 8+c @
// ky2 entirely from LDS; waves w and w+8 both inverse-FFT slot w&7
// (identical redundant writes - benign). Saves a 16MB global round-trip and
// one dispatch vs the 2-kernel version. LDS ~68.6 KB -> 2 blocks/CU
// (32 waves/CU). grid: 16*32 = 512 blocks.
// Hazard ordering: combine reads ar (fwd result) and writes br (dead
// scratch); the inverse FFT's first internal barrier orders all combine
// ar-reads before its stage-0 ar(pong)-writes.
// ---------------------------------------------------------------------------
__global__ __launch_bounds__(1024) void k_cols_fused(const float2* __restrict__ A,
                                                     const float* __restrict__ sum,
                                                     float2* __restrict__ Bf)
{
  constexpr int CS = 260;
  __shared__ float ar[16 * CS], ai[16 * CS], br[16 * CS], bi[16 * CS];
  __shared__ float twfr[128], twfi[128], twvr[128], twvi[128];
  const int tid = threadIdx.x;
  const int lane = tid & 63;
  const int wv = tid >> 6;                       // 0..15
  const int b = blockIdx.x >> 5;
  const int x0 = (blockIdx.x & 31) << 3;
  const float2* Ab = A + ((size_t)b << 16);

  // load own panel (slots 0..7) + mirror panel (slots 8..15)
  for (int i = tid; i < 4096; i += 1024) {
    const int row = i >> 4, c = i & 15;
    const int col = (c < 8) ? (x0 + c) : ((256 - (x0 + (c - 8))) & 255);
    const float2 v = Ab[(row << 8) + col];
    ar[c * CS + row] = v.x;
    ai[c * CS + row] = v.y;
  }
  for (int t = tid; t < 128; t += 1024) {
    float s, c;
    sincosf((float)FWD * (TWO_PI / 256.0f) * (float)t, &s, &c);
    twfr[t] = c; twfi[t] = s;
    twvr[t] = c; twvi[t] = -s;                   // inverse = conj
  }

  // forward FFT: wave w -> slot w (fft's internal first barrier fences loads)
  fft256_stockham(ar + wv * CS, ai + wv * CS, br + wv * CS, bi + wv * CS,
                  twfr, twfi, lane);

  // combine own columns (slots 0..7) -> br/bi
  for (int i = tid; i < 2048; i += 1024) {
    const int ky = i >> 3, c = i & 7;
    const int kx = x0 + c;
    const int ky2 = (256 - ky) & 255;
    const float Zkr = ar[c * CS + ky],        Zki = ai[c * CS + ky];
    const float Zmr = ar[(8 + c) * CS + ky2], Zmi = ai[(8 + c) * CS + ky2];
    const float Xr = 0.5f * (Zkr + Zmr), Xi = 0.5f * (Zki - Zmi);
    const float Yr = 0.5f * (Zki + Zmi), Yi = 0.5f * (Zmr - Zkr);
    const float fx = 0.25f * (float)(kx < 128 ? kx : kx - 256);
    const float fy = 0.25f * (float)(ky < 128 ? ky : ky - 256);
    const float kxv = TWO_PI * fx, kyv = TWO_PI * fy;
    float re, im;
    if ((ky | kx) == 0) {
      re = sum[0]; im = 0.0f;
    } else {
      const float rad = kxv * kxv + kyv * kyv;
      const float sr = Xr * kxv + Yr * kyv;
      const float si = Xi * kxv + Yi * kyv;
      re = si / rad; im = -sr / rad;             // -i*(sr+i*si)/rad
    }
    br[c * CS + ky] = re;
    bi[c * CS + ky] = im;
  }

  // inverse FFT on combined slots 0..7 (waves w and w+8 duplicate slot w&7)
  const int s8 = wv & 7;
  fft256_stockham(br + s8 * CS, bi + s8 * CS, ar + s8 * CS, ai + s8 * CS,
                  twvr, twvi, lane);

  float2* ob = Bf + ((size_t)b << 16) + x0;
  for (int i = tid; i < 2048; i += 1024) {
    const int row = i >> 3, c = i & 7;
    ob[(row << 8) + c] = make_float2(br[c * CS + row], bi[c * CS + row]);
  }
}

// ---------------------------------------------------------------------------
// Inverse ROW FFT, 8 rows per block, fused with extraction:
// u = Re(.)/65536, ut = wtc*c. grid: 512 blocks.
// ---------------------------------------------------------------------------
__global__ __launch_bounds__(512) void k_inv_rows_extract(const float2* __restrict__ Bf,
                                                          const float* __restrict__ in,
                                                          float* __restrict__ u,
                                                          float* __restrict__ ut)
{
  __shared__ float ar[8 * 256], ai[8 * 256], br[8 * 256], bi[8 * 256];
  __shared__ float twr[128], twi[128];
  const int tid = threadIdx.x;
  const int lane = tid & 63;
  const int wv = tid >> 6;
  const int row0 = blockIdx.x << 3;

  for (int i = tid; i < 2048; i += 512) {
    const int r = i >> 8, e = i & 255;
    const float2 v = Bf[((size_t)(row0 + r) << 8) + e];
    ar[(r << 8) + e] = v.x;
    ai[(r << 8) + e] = v.y;
  }
  for (int t = tid; t < 128; t += 512) {
    float s, c;
    sincosf((float)INV * (TWO_PI / 256.0f) * (float)t, &s, &c);
    twr[t] = c; twi[t] = s;
  }
  fft256_stockham(ar + (wv << 8), ai + (wv << 8), br + (wv << 8), bi + (wv << 8),
                  twr, twi, lane);

  for (int i = tid; i < 2048; i += 512) {
    const int r = i >> 8, e = i & 255;
    const int row = row0 + r;
    const int b = row >> 8, y = row & 255;
    const float wtc = in[((size_t)((b << 2) | 2) << 16) + (y << 8) + e];
    const float vc  = in[((size_t)((b << 2) | 3) << 16) + (y << 8) + e];
    u [((size_t)row << 8) + e] = ar[(r << 8) + e] * (1.0f / 65536.0f);
    ut[((size_t)row << 8) + e] = wtc * vc;
  }
}

// ---------------------------------------------------------------------------
// EIGHT fused velocity-Verlet steps, REGISTER-TILED, ONE barrier per step.
// 256 threads = 16x16, each owning a 3x3 cell tile. ut/c2/lap in registers;
// u exchanged via DOUBLE-BUFFERED edge publishes: step j writes u_{j+1}
// edges to W_j (suB for even j, suA for odd j), one __syncthreads, halo
// reads from W_j. WAR safety: publishes to buffer X at step j; the last
// reads of X were step j-2's halo reads, which precede barrier_{j-1}, which
// precedes the publishes (collective barrier argument). lap(u_0) reads suA
// while step 0 publishes suB -> no pre-loop hazard. Validity margins: u_j
// valid at frame-margin j, ut_j at j+1; after 8 steps u_8 on [8,42)^2,
// ut_8 on [9,41)^2 = output tile. FINAL=1 computes energy components
// in-kernel and writes the 4-channel output directly.
// LDS = (2*50*51 + 48*49)*4 = 29808 B -> 4 blocks/CU.
// grid: 16*64 = 1024 blocks x 256 threads (one full occupancy round).
// ---------------------------------------------------------------------------
template <int FINAL>
__global__ __launch_bounds__(256, 4) void k_verlet8(const float* __restrict__ u_in,
                                                    const float* __restrict__ ut_in,
                                                    const float* __restrict__ in,
                                                    float* __restrict__ u_out,
                                                    float* __restrict__ ut_out,
                                                    float* __restrict__ out)
{
  __shared__ float suA[50 * 51];    // u frame, halo 9, stride 51 (initial + odd-j publishes)
  __shared__ float suB[50 * 51];    // even-j publishes + epilogue staging
  __shared__ float tmp[48 * 49];    // staging for ut, then c
  const int tid = threadIdx.x;
  const int b = blockIdx.x >> 6, t = blockIdx.x & 63;
  const int ty0 = (t >> 3) << 5, tx0 = (t & 7) << 5;  // tile origin (global)
  const int ty = tid >> 4, tx = tid & 15;             // 16x16 thread grid
  const int y0 = 1 + 3 * ty, x0 = 1 + 3 * tx;         // u-frame origin of 3x3
  const float* ub  = u_in  + ((size_t)b << 16);
  const float* utb = ut_in + ((size_t)b << 16);
  const float* vb  = in + ((size_t)((b << 2) | 3) << 16);

  // ---- stage u frame (halo 9) -> suA, coalesced
  for (int i = tid; i < 2500; i += 256) {
    const int iy = i / 50, ix = i - iy * 50;
    const int gy = (ty0 + iy - 9) & 255, gx = (tx0 + ix - 9) & 255;
    suA[iy * 51 + ix] = ub[(gy << 8) + gx];
  }
  // ---- stage ut (halo 8) -> tmp, coalesced
  for (int i = tid; i < 2304; i += 256) {
    const int iy = i / 48, ix = i - iy * 48;
    const int gy = (ty0 + iy - 8) & 255, gx = (tx0 + ix - 8) & 255;
    tmp[iy * 49 + ix] = utb[(gy << 8) + gx];
  }
  __syncthreads();

  float uR[3][3], utR[3][3], c2R[3][3], laR[3][3];
#pragma unroll
  for (int r = 0; r < 3; ++r)
#pragma unroll
    for (int c = 0; c < 3; ++c) {
      uR[r][c]  = suA[(y0 + r) * 51 + x0 + c];
      utR[r][c] = tmp[(3 * ty + r) * 49 + 3 * tx + c];
    }
  __syncthreads();
  // ---- stage c -> tmp -> c2 regs (c2 = c*c, as reference)
  for (int i = tid; i < 2304; i += 256) {
    const int iy = i / 48, ix = i - iy * 48;
    const int gy = (ty0 + iy - 8) & 255, gx = (tx0 + ix - 8) & 255;
    tmp[iy * 49 + ix] = vb[(gy << 8) + gx];
  }
  __syncthreads();
#pragma unroll
  for (int r = 0; r < 3; ++r)
#pragma unroll
    for (int c = 0; c < 3; ++c) {
      const float cv = tmp[(3 * ty + r) * 49 + 3 * tx + c];
      c2R[r][c] = cv * cv;
    }

  float hN[3], hS[3], hW[3], hE[3];
  // halo loader: 12 LDS reads (neighbors' edge cells) from buffer U
  auto load_halo = [&](const float* U) {
#pragma unroll
    for (int c = 0; c < 3; ++c) {
      hN[c] = U[(y0 - 1) * 51 + x0 + c];
      hS[c] = U[(y0 + 3) * 51 + x0 + c];
    }
#pragma unroll
    for (int r = 0; r < 3; ++r) {
      hW[r] = U[(y0 + r) * 51 + x0 - 1];
      hE[r] = U[(y0 + r) * 51 + x0 + 3];
    }
  };
  // lap at cell (r,c) in reference fp order: ((((L-2v)+R)+U)-2v)+D)*INV_DX2
  auto lap_cell = [&](int r, int c) -> float {
    const float v = uR[r][c];
    const float L = (c == 0) ? hW[r] : uR[r][c - 1];
    const float R = (c == 2) ? hE[r] : uR[r][c + 1];
    const float U = (r == 0) ? hN[c] : uR[r - 1][c];
    const float D = (r == 2) ? hS[c] : uR[r + 1][c];
    const float t2 = 2.0f * v;
    return (((((L - t2) + R) + U) - t2) + D) * INV_DX2;
  };

  // ---- lap(u_0): halos from suA (fully staged; step 0 publishes suB)
  load_halo(suA);
#pragma unroll
  for (int r = 0; r < 3; ++r)
#pragma unroll
    for (int c = 0; c < 3; ++c) laR[r][c] = lap_cell(r, c);

  // ---- 8 fused steps, ONE barrier each
  for (int j = 0; j < 8; ++j) {
    float* W = (j & 1) ? suA : suB;
    // u_new = (u + dt*ut) + ((hdt2*c2)*lap0)    [registers only]
#pragma unroll
    for (int r = 0; r < 3; ++r)
#pragma unroll
      for (int c = 0; c < 3; ++c)
        uR[r][c] = (uR[r][c] + DTf * utR[r][c]) + (HDT2f * c2R[r][c]) * laR[r][c];
    // publish the 8 edge cells to W
    W[(y0    ) * 51 + x0    ] = uR[0][0];
    W[(y0    ) * 51 + x0 + 1] = uR[0][1];
    W[(y0    ) * 51 + x0 + 2] = uR[0][2];
    W[(y0 + 1) * 51 + x0    ] = uR[1][0];
    W[(y0 + 1) * 51 + x0 + 2] = uR[1][2];
    W[(y0 + 2) * 51 + x0    ] = uR[2][0];
    W[(y0 + 2) * 51 + x0 + 1] = uR[2][1];
    W[(y0 + 2) * 51 + x0 + 2] = uR[2][2];
    __syncthreads();
    load_halo(W);
    // lap1; ut += (hdt*c2)*(lap0+lap1); lap0 <- lap1
#pragma unroll
    for (int r = 0; r < 3; ++r)
#pragma unroll
      for (int c = 0; c < 3; ++c) {
        const float ln = lap_cell(r, c);
        utR[r][c] = utR[r][c] + (HDTf * c2R[r][c]) * (laR[r][c] + ln);
        laR[r][c] = ln;
      }
  }

  // ---- epilogue: stage full u_8 into suB (last halo reads were from suA
  // at j=7 -> disjoint), then barrier, then coalesced/fused output
#pragma unroll
  for (int r = 0; r < 3; ++r)
#pragma unroll
    for (int c = 0; c < 3; ++c) suB[(y0 + r) * 51 + x0 + c] = uR[r][c];
  __syncthreads();

  if (FINAL) {
    // energy components from u_8 (valid on frame [8,42)) + ut_8 (tile)
    float wxv[4], wyv[4];
#pragma unroll
    for (int k = 0; k < 4; ++k) {
      const int i = tid + (k << 8);
      const int oy = i >> 5, ox = i & 31;
      const float uc = suB[(9 + oy) * 51 + 9 + ox];
      wxv[k] = (tx0 + ox == 0) ? 0.0f : (uc - suB[(9 + oy) * 51 + 8 + ox]) * INV_DX;
      wyv[k] = (ty0 + oy == 0) ? 0.0f : (uc - suB[(8 + oy) * 51 + 9 + ox]) * INV_DX;
    }
    __syncthreads();
#pragma unroll
    for (int r = 0; r < 3; ++r)
#pragma unroll
      for (int c = 0; c < 3; ++c) suB[(y0 + r) * 51 + x0 + c] = utR[r][c];
    __syncthreads();
#pragma unroll
    for (int k = 0; k < 4; ++k) {
      const int i = tid + (k << 8);
      const int oy = i >> 5, ox = i & 31;
      const int g = ((ty0 + oy) << 8) + (tx0 + ox);
      const float utv = suB[(9 + oy) * 51 + 9 + ox];
      const float cv  = vb[g];
      out[((size_t)(b << 2) << 16) + g]       = wxv[k];
      out[((size_t)((b << 2) | 1) << 16) + g] = wyv[k];
      out[((size_t)((b << 2) | 2) << 16) + g] = utv / cv;
      out[((size_t)((b << 2) | 3) << 16) + g] = cv;
    }
  } else {
    float* uob  = u_out  + ((size_t)b << 16);
    float* utob = ut_out + ((size_t)b << 16);
    for (int i = tid; i < 1024; i += 256) {
      const int oy = i >> 5, ox = i & 31;
      uob[((ty0 + oy) << 8) + tx0 + ox] = suB[(9 + oy) * 51 + 9 + ox];
    }
    __syncthreads();
#pragma unroll
    for (int r = 0; r < 3; ++r)
#pragma unroll
      for (int c = 0; c < 3; ++c) suB[(y0 + r) * 51 + x0 + c] = utR[r][c];
    __syncthreads();
    for (int i = tid; i < 1024; i += 256) {
      const int oy = i >> 5, ox = i & 31;
      utob[((ty0 + oy) << 8) + tx0 + ox] = suB[(9 + oy) * 51 + 9 + ox];
    }
  }
}

// ---------------------------------------------------------------------------
// Buffer plan — ws requirement: 8 MB. Lifetimes:
//   ws[0:4)       : sumv (memset -> read in k_cols_fused; dead before u0)
//   ws[0:8MB)     : u0/ut0 (written by EVEN verlet steps; read by odd+final)
//   d_out[0:8MB)  : A (fwd spectrum; dead after k_cols_fused), then u1/ut1
//   d_out[8:16MB) : Bf (inv-col spectrum; dead after extract)
//   d_out (full)  : final 4-channel output, written by the FINAL verlet
//                   launch, which reads ONLY ws + in -> no aliasing hazard.
// Pipeline: memset -> rowFFT+pack+sum -> colsFused(fwd+combine+inv) ->
//   inv rowFFT+extract(->d_out lo) -> verlet x8 (even: d_out->ws, odd:
//   ws->d_out; s=7 FINAL: ws->out). 12 dispatches total.
// ---------------------------------------------------------------------------
extern "C" void kernel_launch(void* const* d_in, const int* in_sizes, int n_in,
                              void* d_out, int out_size, void* d_ws, size_t ws_size,
                              hipStream_t stream)
{
  const float* in = (const float*)d_in[0];
  float* out = (float*)d_out;
  char* ws = (char*)d_ws;

  float2* A   = (float2*)d_out;                 // d_out[0:8MB)
  float*  u1  = (float*)d_out;                  // same 8MB, after A dies
  float*  ut1 = u1 + NTOT;
  float2* Bf  = (float2*)((float*)d_out + 2 * NTOT);   // d_out[8:16MB)

  float*  sum = (float*)ws;                     // ws[0:4), dead before u0
  float*  u0  = (float*)ws;                     // ws[0:8MB)
  float*  ut0 = u0 + NTOT;

  hipMemsetAsync(sum, 0, sizeof(float), stream);

  k_fwd_rows_pack<<<NBATCH * 32, 512, 0, stream>>>(in, A, sum);
  k_cols_fused<<<NBATCH * 32, 1024, 0, stream>>>(A, sum, Bf);
  k_inv_rows_extract<<<NBATCH * 32, 512, 0, stream>>>(Bf, in, u1, ut1);

  // 64 Verlet steps = 8 launches x 8 fused steps.
  // even s: (u1,ut1)[d_out] -> (u0,ut0)[ws]; odd s<7: ws -> d_out;
  // s=7 (FINAL): ws -> out (fused energy + output assembly).
  for (int s = 0; s < 7; ++s) {
    if (s & 1) k_verlet8<0><<<NBATCH * 64, 256, 0, stream>>>(u0, ut0, in, u1, ut1, out);
    else       k_verlet8<0><<<NBATCH * 64, 256, 0, stream>>>(u1, ut1, in, u0, ut0, out);
  }
  k_verlet8<1><<<NBATCH * 64, 256, 0, stream>>>(u0, ut0, in, u1, ut1, out);
}